// Round 11
// baseline (157.346 us; speedup 1.0000x reference)
//
#include <hip/hip_runtime.h>
#include <hip/hip_bf16.h>

#define S_LEN 2048
#define DIM_  2048
#define NH    32
#define NKV   8
#define HD    64

typedef __bf16 bf16x8 __attribute__((ext_vector_type(8)));
typedef __bf16 bf16x4 __attribute__((ext_vector_type(4)));
typedef float  f32x4  __attribute__((ext_vector_type(4)));

#define AS_GLOBAL(p) ((const __attribute__((address_space(1))) void*)(p))
#define AS_LDS(p)    ((__attribute__((address_space(3))) void*)(p))

// ---------------- fp32 -> bf16 conversion (x, wq|wk|wv concat, wo) ----------
__global__ __launch_bounds__(256) void cvt_xw(
    const float* __restrict__ x,  const float* __restrict__ wq,
    const float* __restrict__ wk, const float* __restrict__ wv,
    const float* __restrict__ wo,
    __bf16* __restrict__ xb, __bf16* __restrict__ wb, __bf16* __restrict__ wob)
{
  size_t i = (size_t)blockIdx.x * 256 + threadIdx.x;
  const float* src; __bf16* dst; size_t off;
  if (i < 1048576)      { src = x;  dst = xb;            off = i; }
  else if (i < 2097152) { src = wq; dst = wb;            off = i - 1048576; }
  else if (i < 2359296) { src = wk; dst = wb + 4194304;  off = i - 2097152; }
  else if (i < 2621440) { src = wv; dst = wb + 5242880;  off = i - 2359296; }
  else                  { src = wo; dst = wob;           off = i - 2621440; }
  float4 f = ((const float4*)src)[off];
  bf16x4 r;
  r[0] = (__bf16)f.x; r[1] = (__bf16)f.y; r[2] = (__bf16)f.z; r[3] = (__bf16)f.w;
  ((bf16x4*)dst)[off] = r;
}

// ---- 128x128 bf16 GEMM, BK=32, 256 thr / 4 waves (64x64 each), 3-buffer ----
// T4 pipeline: ONE raw s_barrier per K-step, counted s_waitcnt vmcnt(8) —
// staging loads stay in flight ACROSS barriers (2 tiles ahead, 3 LDS bufs).
// Tile read at iter t was staged at iter t-2 -> landed once <=8 vm ops remain.
#define BKG   32
#define TILEG 4096   // 128*32 elems (8 KB)

// 256 threads stage one 128x32 tile: two 16B chunks each (2 vm ops/wave).
__device__ __forceinline__ void stageG(
    const __bf16* __restrict__ g, int row0, int k0, int ld, __bf16* lds)
{
  const int tid  = threadIdx.x;
  const int wave = tid >> 6;
#pragma unroll
  for (int iss = 0; iss < 2; ++iss) {
    int off = (iss * 256 + tid) * 16;   // byte offset in 8 KB tile
    int r = off >> 6;                   // 64 B per row (32 bf16)
    int c = (off & 63) >> 1;
    __builtin_amdgcn_global_load_lds(
        AS_GLOBAL(g + (size_t)(row0 + r) * ld + k0 + c),
        AS_LDS(lds + iss * 2048 + wave * 512),   // wave-uniform base + lane*16
        16, 0, 0);
  }
}

__device__ __forceinline__ void gemm_pipe(
    const __bf16* __restrict__ A, const __bf16* __restrict__ B,
    int row0, int col0, int ld, int nt,
    __bf16* As, __bf16* Bs, f32x4 acc[4][4])
{
  const int lane = threadIdx.x & 63;
  const int wave = threadIdx.x >> 6;
  const int wr = wave >> 1, wc = wave & 1;   // 2x2 wave grid, 64x64 each
  const int fr = lane & 15, fg = lane >> 4;

  // prologue: stage tiles 0,1 into bufs 0,1 (8 vm ops/wave outstanding)
  stageG(A, row0, 0, ld, As);
  stageG(B, col0, 0, ld, Bs);
  stageG(A, row0, BKG, ld, As + TILEG);
  stageG(B, col0, BKG, ld, Bs + TILEG);

  int cur = 0, pb = 2;
  for (int t = 0; t < nt; ++t) {
    // barrier first: all waves done READING buf[pb] (read 3 iters ago)
    asm volatile("" ::: "memory");
    __builtin_amdgcn_s_barrier();
    asm volatile("" ::: "memory");

    // stage tile t+2 (clamped junk in last 2 iters -> constant vmcnt)
    const int tn = (t + 2 < nt) ? t + 2 : nt - 1;
    stageG(A, row0, tn * BKG, ld, As + pb * TILEG);
    stageG(B, col0, tn * BKG, ld, Bs + pb * TILEG);

    // counted wait: tile t (staged 2 iters ago) landed; 8 newer ops may fly
    asm volatile("s_waitcnt vmcnt(8)" ::: "memory");

    bf16x8 a[4], b[4];
#pragma unroll
    for (int mi = 0; mi < 4; ++mi)
      a[mi] = *(const bf16x8*)(As + cur * TILEG + (wr * 64 + mi * 16 + fr) * 32 + fg * 8);
#pragma unroll
    for (int ni = 0; ni < 4; ++ni)
      b[ni] = *(const bf16x8*)(Bs + cur * TILEG + (wc * 64 + ni * 16 + fr) * 32 + fg * 8);
#pragma unroll
    for (int mi = 0; mi < 4; ++mi)
#pragma unroll
      for (int ni = 0; ni < 4; ++ni)
        acc[mi][ni] = __builtin_amdgcn_mfma_f32_16x16x32_bf16(a[mi], b[ni], acc[mi][ni], 0, 0, 0);

    cur = (cur == 2) ? 0 : cur + 1;
    pb  = (pb  == 2) ? 0 : pb  + 1;
  }
}

// ---------------- QKV projection (bf16, 384 blocks, XCD col-swizzle) --------
__global__ __launch_bounds__(256) void qkv_gemm(
    const __bf16* __restrict__ xb, const __bf16* __restrict__ wb,
    __bf16* __restrict__ q_buf, __bf16* __restrict__ k_buf, __bf16* __restrict__ v_buf)
{
  __shared__ __bf16 As[3 * TILEG];   // 24 KB
  __shared__ __bf16 Bs[3 * TILEG];   // 24 KB
  const int lane = threadIdx.x & 63;
  const int wave = threadIdx.x >> 6;
  const int wr = wave >> 1, wc = wave & 1;
  const int fr = lane & 15, fg = lane >> 4;

  // per XCD: 3 col-panels x 16 row-tiles -> B slice (1.5 MB) L2-resident
  const int lid = blockIdx.x;        // 0..383
  const int xcd = lid & 7;
  const int j   = lid >> 3;          // 0..47
  const int col0 = (xcd * 3 + (j >> 4)) * 128;
  const int row0 = (j & 15) * 128;

  f32x4 acc[4][4] = {};
  gemm_pipe(xb, wb, row0, col0, DIM_, DIM_ / BKG, As, Bs, acc);

  const int rowg0 = row0 + wr * 64;
  const int colg0 = col0 + wc * 64;
#pragma unroll
  for (int mi = 0; mi < 4; ++mi) {
#pragma unroll
    for (int ni = 0; ni < 4; ++ni) {
#pragma unroll
      for (int j2 = 0; j2 < 4; ++j2) {
        int row = rowg0 + mi * 16 + fg * 4 + j2;
        int col = colg0 + ni * 16 + fr;
        float v = acc[mi][ni][j2];
        if (col < 2048) {
          int h = col >> 6, d = col & 63;
          q_buf[((size_t)h * S_LEN + row) * HD + d] = (__bf16)v;
        } else if (col < 2560) {
          int c = col - 2048, g = c >> 6, d = c & 63;
          k_buf[((size_t)g * S_LEN + row) * HD + d] = (__bf16)v;
        } else {
          int c = col - 2560, g = c >> 6, d = c & 63;
          v_buf[((size_t)g * HD + d) * S_LEN + row] = (__bf16)v;  // transposed
        }
      }
    }
  }
}

// ---------------- Output projection (bf16, 256 blocks, XCD col-swizzle) -----
__global__ __launch_bounds__(256) void oproj_gemm(
    const __bf16* __restrict__ attn_buf, const __bf16* __restrict__ wob,
    float* __restrict__ out)
{
  __shared__ __bf16 As[3 * TILEG];
  __shared__ __bf16 Bs[3 * TILEG];
  const int lane = threadIdx.x & 63;
  const int wave = threadIdx.x >> 6;
  const int wr = wave >> 1, wc = wave & 1;
  const int fr = lane & 15, fg = lane >> 4;

  const int lid = blockIdx.x;        // 0..255
  const int xcd = lid & 7;
  const int j   = lid >> 3;          // 0..31
  const int col0 = (xcd * 2 + (j >> 4)) * 128;
  const int row0 = (j & 15) * 128;

  f32x4 acc[4][4] = {};
  gemm_pipe(attn_buf, wob, row0, col0, DIM_, DIM_ / BKG, As, Bs, acc);

  const int rowg0 = row0 + wr * 64;
  const int colg0 = col0 + wc * 64;
#pragma unroll
  for (int mi = 0; mi < 4; ++mi)
#pragma unroll
    for (int ni = 0; ni < 4; ++ni)
#pragma unroll
      for (int j2 = 0; j2 < 4; ++j2) {
        int row = rowg0 + mi * 16 + fg * 4 + j2;
        int col = colg0 + ni * 16 + fr;
        out[(size_t)row * DIM_ + col] = acc[mi][ni][j2];
      }
}

// ---------------- RoPE on K only (in place, bf16); Q fused into attn --------
__global__ __launch_bounds__(256) void rope_k(
    __bf16* __restrict__ k_buf, const float* __restrict__ fc)
{
  int idx = blockIdx.x * 256 + threadIdx.x;
  int i    = idx & 31;
  int sp   = (idx >> 5) & (S_LEN - 1);
  int g    = idx >> 16;
  __bf16* buf = k_buf + ((size_t)g * S_LEN + sp) * HD;
  float c = fc[(sp * 32 + i) * 2 + 0];
  float s = fc[(sp * 32 + i) * 2 + 1];
  float x1 = (float)buf[2 * i], x2 = (float)buf[2 * i + 1];
  buf[2 * i + 0] = (__bf16)(x1 * c - x2 * s);
  buf[2 * i + 1] = (__bf16)(x1 * s + x2 * c);
}

// ---------------- Flash attention (causal, GQA, swapped-QK, shared KV) ------
// 1-D grid 512, PAIRED dispatch: blocks 0..255 = long q-tiles, 256..511 short.
__global__ __launch_bounds__(512) void attn_kernel(
    const __bf16* __restrict__ q_buf, const __bf16* __restrict__ k_buf,
    const __bf16* __restrict__ v_buf, const float* __restrict__ fc,
    __bf16* __restrict__ attn_buf)
{
  __shared__ __align__(16) __bf16 Ks[2][64 * 64];   // 2 x 8 KB
  __shared__ __align__(16) __bf16 Vs[2][64 * 64];   // 2 x 8 KB (V^T: [d][kv])
  __shared__ __align__(16) __bf16 lds_p[8][16][72]; // per-wave P slab

  const int tid  = threadIdx.x;
  const int lane = tid & 63;
  const int wave = tid >> 6;
  const int n = blockIdx.x;
  const int qt = (n < 256) ? (15 - (n >> 5)) : ((n - 256) >> 5);
  const int h  = n & 31;
  const int g = h >> 2;             // NREP = 4
  const int r0 = qt * 128 + wave * 16;
  const int lrow = lane & 15;
  const int lgrp = lane >> 4;
  const int lk = lgrp * 8;

  const __bf16* qh = q_buf + (size_t)h * S_LEN * HD;
  const __bf16* kh = k_buf + (size_t)g * S_LEN * HD;
  const __bf16* vh = v_buf + (size_t)g * HD * S_LEN;

  const int sr   = tid >> 3;            // staging row 0..63
  const int scol = tid & 7;             // source 16B chunk
  const int dcol = scol ^ (sr & 7);     // swizzled dest chunk

  // ---- load Q fragment + apply RoPE in-register ----
  bf16x8 qa[2];
  const float* fcrow = fc + (size_t)(r0 + lrow) * 64;
#pragma unroll
  for (int kk = 0; kk < 2; ++kk) {
    qa[kk] = *(const bf16x8*)(qh + (size_t)(r0 + lrow) * HD + kk * 32 + lk);
    float4 cs0 = *(const float4*)(fcrow + (kk * 16 + lgrp * 4) * 2);
    float4 cs1 = *(const float4*)(fcrow + (kk * 16 + lgrp * 4) * 2 + 4);
    float cc[4] = {cs0.x, cs0.z, cs1.x, cs1.z};
    float ss[4] = {cs0.y, cs0.w, cs1.y, cs1.w};
#pragma unroll
    for (int pr = 0; pr < 4; ++pr) {
      float x1 = (float)qa[kk][2 * pr], x2 = (float)qa[kk][2 * pr + 1];
      qa[kk][2 * pr]     = (__bf16)(x1 * cc[pr] - x2 * ss[pr]);
      qa[kk][2 * pr + 1] = (__bf16)(x1 * ss[pr] + x2 * cc[pr]);
    }
  }

  const float KS = 0.125f * 1.44269504088896f;  // scale * log2(e)
  float m_col = -3.0e38f, l_col = 0.f;
  f32x4 oacc[4] = {};

  const int nt = 2 * qt + 2;

  {
    uint4 k0 = *(const uint4*)(kh + (size_t)sr * HD + scol * 8);
    uint4 v0 = *(const uint4*)(vh + (size_t)sr * S_LEN + scol * 8);
    *(uint4*)(&Ks[0][sr * 64 + dcol * 8]) = k0;
    *(uint4*)(&Vs[0][sr * 64 + dcol * 8]) = v0;
  }
  __syncthreads();

  for (int t = 0; t < nt; ++t) {
    const int cur = t & 1;
    const int t0 = t * 64;

    const int tn0 = (t + 1 < nt ? t + 1 : t) * 64;
    uint4 kreg = *(const uint4*)(kh + (size_t)(tn0 + sr) * HD + scol * 8);
    uint4 vreg = *(const uint4*)(vh + (size_t)sr * S_LEN + tn0 + scol * 8);

    const int dmax = r0 + 15 - t0;
    if (dmax >= 0) {
      f32x4 sc[4] = {};
      const int cmax = dmax >> 4;
      __builtin_amdgcn_s_setprio(1);
#pragma unroll
      for (int c = 0; c < 4; ++c) {
        if (c <= cmax) {
#pragma unroll
          for (int kk = 0; kk < 2; ++kk) {
            bf16x8 ka = *(const bf16x8*)(
                &Ks[cur][(c * 16 + lrow) * 64 + (((kk * 4 + lgrp) ^ (lrow & 7)) * 8)]);
            sc[c] = __builtin_amdgcn_mfma_f32_16x16x32_bf16(ka, qa[kk], sc[c], 0, 0, 0);
          }
        }
      }
      __builtin_amdgcn_s_setprio(0);

      float p[16];
      const int q = r0 + lrow;
      if (t0 + 63 <= r0) {
#pragma unroll
        for (int c = 0; c < 4; ++c)
#pragma unroll
          for (int j = 0; j < 4; ++j)
            p[c * 4 + j] = sc[c][j] * KS;
      } else {
#pragma unroll
        for (int c = 0; c < 4; ++c)
#pragma unroll
          for (int j = 0; j < 4; ++j) {
            int kv = t0 + c * 16 + lgrp * 4 + j;
            p[c * 4 + j] = (kv <= q) ? sc[c][j] * KS : -3.0e38f;
          }
      }

      float m8[8], m4[4];
#pragma unroll
      for (int i = 0; i < 8; ++i) m8[i] = fmaxf(p[i], p[i + 8]);
#pragma unroll
      for (int i = 0; i < 4; ++i) m4[i] = fmaxf(m8[i], m8[i + 4]);
      float mx = fmaxf(fmaxf(m4[0], m4[1]), fmaxf(m4[2], m4[3]));
      mx = fmaxf(mx, __shfl_xor(mx, 16, 64));
      mx = fmaxf(mx, __shfl_xor(mx, 32, 64));

      if (__all(mx <= m_col + 8.f)) {
        // defer: alpha == 1
      } else {
        float nm = fmaxf(m_col, mx);
        float alpha = __builtin_amdgcn_exp2f(m_col - nm);
        m_col = nm;
        float ar[4];
#pragma unroll
        for (int j = 0; j < 4; ++j)
          ar[j] = __shfl(alpha, lgrp * 4 + j, 64);
#pragma unroll
        for (int nf = 0; nf < 4; ++nf)
#pragma unroll
          for (int j = 0; j < 4; ++j)
            oacc[nf][j] *= ar[j];
        l_col *= alpha;
      }

#pragma unroll
      for (int i = 0; i < 16; ++i)
        p[i] = __builtin_amdgcn_exp2f(p[i] - m_col);
      float s8[8], s4[4];
#pragma unroll
      for (int i = 0; i < 8; ++i) s8[i] = p[i] + p[i + 8];
#pragma unroll
      for (int i = 0; i < 4; ++i) s4[i] = s8[i] + s8[i + 4];
      float rs = (s4[0] + s4[1]) + (s4[2] + s4[3]);
      rs += __shfl_xor(rs, 16, 64);
      rs += __shfl_xor(rs, 32, 64);
      l_col += rs;

#pragma unroll
      for (int c = 0; c < 4; ++c)
#pragma unroll
        for (int e = 0; e < 2; ++e) {
          union { __bf16 hh[2]; unsigned u; } pk;
          pk.hh[0] = (__bf16)p[c * 4 + 2 * e];
          pk.hh[1] = (__bf16)p[c * 4 + 2 * e + 1];
          *(unsigned*)&lds_p[wave][lrow][c * 16 + lgrp * 4 + 2 * e] = pk.u;
        }
      asm volatile("s_waitcnt lgkmcnt(0)" ::: "memory");

      bf16x8 pa0 = *(const bf16x8*)&lds_p[wave][lrow][lk];
      __builtin_amdgcn_s_setprio(1);
#pragma unroll
      for (int nf = 0; nf < 4; ++nf) {
        bf16x8 vb = *(const bf16x8*)(
            &Vs[cur][(nf * 16 + lrow) * 64 + ((lgrp ^ (lrow & 7)) * 8)]);
        oacc[nf] = __builtin_amdgcn_mfma_f32_16x16x32_bf16(pa0, vb, oacc[nf], 0, 0, 0);
      }
      __builtin_amdgcn_s_setprio(0);
      if (dmax >= 32) {
        bf16x8 pa1 = *(const bf16x8*)&lds_p[wave][lrow][32 + lk];
        __builtin_amdgcn_s_setprio(1);
#pragma unroll
        for (int nf = 0; nf < 4; ++nf) {
          bf16x8 vb = *(const bf16x8*)(
              &Vs[cur][(nf * 16 + lrow) * 64 + (((4 + lgrp) ^ (lrow & 7)) * 8)]);
          oacc[nf] = __builtin_amdgcn_mfma_f32_16x16x32_bf16(pa1, vb, oacc[nf], 0, 0, 0);
        }
        __builtin_amdgcn_s_setprio(0);
      }
    }

    *(uint4*)(&Ks[cur ^ 1][sr * 64 + dcol * 8]) = kreg;
    *(uint4*)(&Vs[cur ^ 1][sr * 64 + dcol * 8]) = vreg;
    __syncthreads();
  }

  float rlr[4];
#pragma unroll
  for (int j = 0; j < 4; ++j)
    rlr[j] = 1.0f / __shfl(l_col, lgrp * 4 + j, 64);
#pragma unroll
  for (int nf = 0; nf < 4; ++nf)
#pragma unroll
    for (int j = 0; j < 4; ++j) {
      int row = r0 + lgrp * 4 + j;
      attn_buf[(size_t)row * (NH * HD) + h * HD + nf * 16 + lrow] =
          (__bf16)(oacc[nf][j] * rlr[j]);
    }
}

extern "C" void kernel_launch(void* const* d_in, const int* in_sizes, int n_in,
                              void* d_out, int out_size, void* d_ws, size_t ws_size,
                              hipStream_t stream)
{
  const float* x  = (const float*)d_in[0];
  const float* wq = (const float*)d_in[1];
  const float* wk = (const float*)d_in[2];
  const float* wv = (const float*)d_in[3];
  const float* wo = (const float*)d_in[4];
  const float* fc = (const float*)d_in[5];
  float* out = (float*)d_out;

  char* ws = (char*)d_ws;
  __bf16* q_buf    = (__bf16*)(ws);                       //  8 MB [NH][S][HD]
  __bf16* k_buf    = (__bf16*)(ws +  8u * 1024 * 1024);   //  2 MB [NKV][S][HD]
  __bf16* v_buf    = (__bf16*)(ws + 10u * 1024 * 1024);   //  2 MB [NKV][HD][S]
  __bf16* attn_buf = (__bf16*)(ws + 12u * 1024 * 1024);   //  8 MB [S][NH*HD]
  __bf16* xb       = (__bf16*)(ws + 20u * 1024 * 1024);   //  8 MB [S][DIM]
  __bf16* wb       = (__bf16*)(ws + 28u * 1024 * 1024);   // 12 MB [3072][DIM]
  __bf16* wob      = (__bf16*)(ws + 40u * 1024 * 1024);   //  8 MB [DIM][DIM]

  cvt_xw<<<dim3(14336), 256, 0, stream>>>(x, wq, wk, wv, wo, xb, wb, wob);
  qkv_gemm<<<dim3(384), 256, 0, stream>>>(xb, wb, q_buf, k_buf, v_buf);
  rope_k<<<dim3(2048), 256, 0, stream>>>(k_buf, fc);
  attn_kernel<<<dim3(512), 512, 0, stream>>>(q_buf, k_buf, v_buf, fc, attn_buf);
  oproj_gemm<<<dim3(256), 256, 0, stream>>>(attn_buf, wob, out);
}

// Round 12
// 149.044 us; speedup vs baseline: 1.0557x; 1.0557x over previous
//
#include <hip/hip_runtime.h>
#include <hip/hip_bf16.h>

#define S_LEN 2048
#define DIM_  2048
#define NH    32
#define NKV   8
#define HD    64

typedef __bf16 bf16x8 __attribute__((ext_vector_type(8)));
typedef __bf16 bf16x4 __attribute__((ext_vector_type(4)));
typedef float  f32x4  __attribute__((ext_vector_type(4)));

#define AS_GLOBAL(p) ((const __attribute__((address_space(1))) void*)(p))
#define AS_LDS(p)    ((__attribute__((address_space(3))) void*)(p))

// ---------------- fp32 -> bf16 conversion (x, wq|wk|wv concat, wo) ----------
// Grid-stride: 1792 blocks x 256 thr x 8 float4 = 3,670,016 float4.
__global__ __launch_bounds__(256) void cvt_xw(
    const float* __restrict__ x,  const float* __restrict__ wq,
    const float* __restrict__ wk, const float* __restrict__ wv,
    const float* __restrict__ wo,
    __bf16* __restrict__ xb, __bf16* __restrict__ wb, __bf16* __restrict__ wob)
{
  const size_t stride = 458752;   // 1792 * 256
  size_t base = (size_t)blockIdx.x * 256 + threadIdx.x;
#pragma unroll
  for (int k = 0; k < 8; ++k) {
    size_t i = base + (size_t)k * stride;
    const float* src; __bf16* dst; size_t off;
    if (i < 1048576)      { src = x;  dst = xb;            off = i; }
    else if (i < 2097152) { src = wq; dst = wb;            off = i - 1048576; }
    else if (i < 2359296) { src = wk; dst = wb + 4194304;  off = i - 2097152; }
    else if (i < 2621440) { src = wv; dst = wb + 5242880;  off = i - 2359296; }
    else                  { src = wo; dst = wob;           off = i - 2621440; }
    float4 f = ((const float4*)src)[off];
    bf16x4 r;
    r[0] = (__bf16)f.x; r[1] = (__bf16)f.y; r[2] = (__bf16)f.z; r[3] = (__bf16)f.w;
    ((bf16x4*)dst)[off] = r;
  }
}

// ------- 128x64 bf16 GEMM tile, BK=32, 256 thr / 4 waves, global_load_lds ---
#define BK 32
#define TA_ELEMS 4096   // 128*32 A tile
#define TB_ELEMS 2048   //  64*32 B tile

// 256 threads stage a 128x32 tile (8 KB): two 16B chunks each.
__device__ __forceinline__ void stage_A(
    const __bf16* __restrict__ g, int row0, int k0, int ld, __bf16* lds)
{
  const int tid = threadIdx.x;
  const int wave = tid >> 6;
#pragma unroll
  for (int iss = 0; iss < 2; ++iss) {
    int off = (iss * 256 + tid) * 16;   // byte offset in 8 KB tile
    int r = off >> 6;                   // 64 B per row (32 bf16)
    int c = (off & 63) >> 1;
    __builtin_amdgcn_global_load_lds(
        AS_GLOBAL(g + (size_t)(row0 + r) * ld + k0 + c),
        AS_LDS(lds + iss * 2048 + wave * 512),   // wave-uniform base + lane*16
        16, 0, 0);
  }
}

// 256 threads stage a 64x32 tile (4 KB): one 16B chunk each.
__device__ __forceinline__ void stage_B(
    const __bf16* __restrict__ g, int row0, int k0, int ld, __bf16* lds)
{
  const int tid = threadIdx.x;
  int off = tid * 16;
  int r = off >> 6;
  int c = (off & 63) >> 1;
  __builtin_amdgcn_global_load_lds(
      AS_GLOBAL(g + (size_t)(row0 + r) * ld + k0 + c),
      AS_LDS(lds + (tid >> 6) * 512), 16, 0, 0);
}

__device__ __forceinline__ void gemm_mainloop(
    const __bf16* __restrict__ A, const __bf16* __restrict__ B,
    int row0, int col0, int lda, int ldb, int nt,
    __bf16* As, __bf16* Bs, f32x4 acc[4][2])
{
  const int lane = threadIdx.x & 63;
  const int wave = threadIdx.x >> 6;
  const int wr = wave >> 1, wc = wave & 1;   // 2x2 wave grid
  const int fr = lane & 15, fg = lane >> 4;

  stage_A(A, row0, 0, lda, As);
  stage_B(B, col0, 0, ldb, Bs);

  for (int t = 0; t < nt; ++t) {
    const int cur = t & 1;
    if (t + 1 < nt) {
      stage_A(A, row0, (t + 1) * BK, lda, As + (cur ^ 1) * TA_ELEMS);
      stage_B(B, col0, (t + 1) * BK, ldb, Bs + (cur ^ 1) * TB_ELEMS);
    }
    __syncthreads();
    bf16x8 a[4], b[2];
#pragma unroll
    for (int mi = 0; mi < 4; ++mi)
      a[mi] = *(const bf16x8*)(As + cur * TA_ELEMS + (wr * 64 + mi * 16 + fr) * 32 + fg * 8);
#pragma unroll
    for (int ni = 0; ni < 2; ++ni)
      b[ni] = *(const bf16x8*)(Bs + cur * TB_ELEMS + (wc * 32 + ni * 16 + fr) * 32 + fg * 8);
#pragma unroll
    for (int mi = 0; mi < 4; ++mi)
#pragma unroll
      for (int ni = 0; ni < 2; ++ni)
        acc[mi][ni] = __builtin_amdgcn_mfma_f32_16x16x32_bf16(a[mi], b[ni], acc[mi][ni], 0, 0, 0);
    __syncthreads();
  }
}

// ---------------- QKV projection (bf16, 768 blocks = 3/CU) ------------------
__global__ __launch_bounds__(256) void qkv_gemm(
    const __bf16* __restrict__ xb, const __bf16* __restrict__ wb,
    __bf16* __restrict__ q_buf, __bf16* __restrict__ k_buf, __bf16* __restrict__ v_buf)
{
  __shared__ __bf16 As[2 * TA_ELEMS];
  __shared__ __bf16 Bs[2 * TB_ELEMS];
  const int lane = threadIdx.x & 63;
  const int wave = threadIdx.x >> 6;
  const int wr = wave >> 1, wc = wave & 1;
  const int fr = lane & 15, fg = lane >> 4;

  const int lid = blockIdx.x;        // 0..767
  const int xcd = lid & 7;
  const int i   = lid >> 3;          // 0..95
  const int row0 = (i & 15) * 128;
  const int col0 = (xcd * 6 + (i >> 4)) * 64;

  f32x4 acc[4][2] = {};
  gemm_mainloop(xb, wb, row0, col0, DIM_, DIM_, DIM_ / BK, As, Bs, acc);

  const int rowg0 = row0 + wr * 64;
  const int colg0 = col0 + wc * 32;
#pragma unroll
  for (int mi = 0; mi < 4; ++mi) {
#pragma unroll
    for (int ni = 0; ni < 2; ++ni) {
#pragma unroll
      for (int j = 0; j < 4; ++j) {
        int row = rowg0 + mi * 16 + fg * 4 + j;
        int col = colg0 + ni * 16 + fr;
        float v = acc[mi][ni][j];
        if (col < 2048) {
          int h = col >> 6, d = col & 63;
          q_buf[((size_t)h * S_LEN + row) * HD + d] = (__bf16)v;
        } else if (col < 2560) {
          int c = col - 2048, g = c >> 6, d = c & 63;
          k_buf[((size_t)g * S_LEN + row) * HD + d] = (__bf16)v;
        } else {
          int c = col - 2560, g = c >> 6, d = c & 63;
          v_buf[((size_t)g * HD + d) * S_LEN + row] = (__bf16)v;  // transposed
        }
      }
    }
  }
}

// ---------------- Output projection (bf16, 512 blocks = 2/CU) ---------------
__global__ __launch_bounds__(256) void oproj_gemm(
    const __bf16* __restrict__ attn_buf, const __bf16* __restrict__ wob,
    float* __restrict__ out)
{
  __shared__ __bf16 As[2 * TA_ELEMS];
  __shared__ __bf16 Bs[2 * TB_ELEMS];
  const int lane = threadIdx.x & 63;
  const int wave = threadIdx.x >> 6;
  const int wr = wave >> 1, wc = wave & 1;
  const int fr = lane & 15, fg = lane >> 4;

  const int lid = blockIdx.x;        // 0..511
  const int xcd = lid & 7;
  const int i   = lid >> 3;          // 0..63
  const int row0 = (i & 15) * 128;
  const int col0 = (xcd * 4 + (i >> 4)) * 64;

  f32x4 acc[4][2] = {};
  gemm_mainloop(attn_buf, wob, row0, col0, DIM_, DIM_, DIM_ / BK, As, Bs, acc);

  const int rowg0 = row0 + wr * 64;
  const int colg0 = col0 + wc * 32;
#pragma unroll
  for (int mi = 0; mi < 4; ++mi)
#pragma unroll
    for (int ni = 0; ni < 2; ++ni)
#pragma unroll
      for (int j = 0; j < 4; ++j) {
        int row = rowg0 + mi * 16 + fg * 4 + j;
        int col = colg0 + ni * 16 + fr;
        out[(size_t)row * DIM_ + col] = acc[mi][ni][j];
      }
}

// ---------------- RoPE on K only (in place, bf16); Q fused into attn --------
__global__ __launch_bounds__(256) void rope_k(
    __bf16* __restrict__ k_buf, const float* __restrict__ fc)
{
  int idx = blockIdx.x * 256 + threadIdx.x;
  int i    = idx & 31;
  int sp   = (idx >> 5) & (S_LEN - 1);
  int g    = idx >> 16;
  __bf16* buf = k_buf + ((size_t)g * S_LEN + sp) * HD;
  float c = fc[(sp * 32 + i) * 2 + 0];
  float s = fc[(sp * 32 + i) * 2 + 1];
  float x1 = (float)buf[2 * i], x2 = (float)buf[2 * i + 1];
  buf[2 * i + 0] = (__bf16)(x1 * c - x2 * s);
  buf[2 * i + 1] = (__bf16)(x1 * s + x2 * c);
}

// ---------------- Flash attention (causal, GQA, swapped-QK, shared KV) ------
// 1-D grid 512, PAIRED dispatch: blocks 0..255 = long q-tiles, 256..511 short.
// Q-RoPE coefficients pre-multiplied by scale*log2(e) -> no per-tile scaling.
__global__ __launch_bounds__(512) void attn_kernel(
    const __bf16* __restrict__ q_buf, const __bf16* __restrict__ k_buf,
    const __bf16* __restrict__ v_buf, const float* __restrict__ fc,
    __bf16* __restrict__ attn_buf)
{
  __shared__ __align__(16) __bf16 Ks[2][64 * 64];   // 2 x 8 KB
  __shared__ __align__(16) __bf16 Vs[2][64 * 64];   // 2 x 8 KB (V^T: [d][kv])
  __shared__ __align__(16) __bf16 lds_p[8][16][72]; // per-wave P slab

  const int tid  = threadIdx.x;
  const int lane = tid & 63;
  const int wave = tid >> 6;
  const int n = blockIdx.x;
  const int qt = (n < 256) ? (15 - (n >> 5)) : ((n - 256) >> 5);
  const int h  = n & 31;
  const int g = h >> 2;             // NREP = 4
  const int r0 = qt * 128 + wave * 16;
  const int lrow = lane & 15;
  const int lgrp = lane >> 4;
  const int lk = lgrp * 8;

  const __bf16* qh = q_buf + (size_t)h * S_LEN * HD;
  const __bf16* kh = k_buf + (size_t)g * S_LEN * HD;
  const __bf16* vh = v_buf + (size_t)g * HD * S_LEN;

  const int sr   = tid >> 3;            // staging row 0..63
  const int scol = tid & 7;             // source 16B chunk
  const int dcol = scol ^ (sr & 7);     // swizzled dest chunk

  // ---- load Q fragment + RoPE with KS-folded coefficients ----
  const float KS = 0.125f * 1.44269504088896f;  // scale * log2(e)
  bf16x8 qa[2];
  const float* fcrow = fc + (size_t)(r0 + lrow) * 64;
#pragma unroll
  for (int kk = 0; kk < 2; ++kk) {
    qa[kk] = *(const bf16x8*)(qh + (size_t)(r0 + lrow) * HD + kk * 32 + lk);
    float4 cs0 = *(const float4*)(fcrow + (kk * 16 + lgrp * 4) * 2);
    float4 cs1 = *(const float4*)(fcrow + (kk * 16 + lgrp * 4) * 2 + 4);
    float cc[4] = {cs0.x * KS, cs0.z * KS, cs1.x * KS, cs1.z * KS};
    float ss[4] = {cs0.y * KS, cs0.w * KS, cs1.y * KS, cs1.w * KS};
#pragma unroll
    for (int pr = 0; pr < 4; ++pr) {
      float x1 = (float)qa[kk][2 * pr], x2 = (float)qa[kk][2 * pr + 1];
      qa[kk][2 * pr]     = (__bf16)(x1 * cc[pr] - x2 * ss[pr]);
      qa[kk][2 * pr + 1] = (__bf16)(x1 * ss[pr] + x2 * cc[pr]);
    }
  }

  float m_col = -3.0e38f, l_col = 0.f;
  f32x4 oacc[4] = {};

  const int nt = 2 * qt + 2;

  {
    uint4 k0 = *(const uint4*)(kh + (size_t)sr * HD + scol * 8);
    uint4 v0 = *(const uint4*)(vh + (size_t)sr * S_LEN + scol * 8);
    *(uint4*)(&Ks[0][sr * 64 + dcol * 8]) = k0;
    *(uint4*)(&Vs[0][sr * 64 + dcol * 8]) = v0;
  }
  __syncthreads();

  for (int t = 0; t < nt; ++t) {
    const int cur = t & 1;
    const int t0 = t * 64;

    const int tn0 = (t + 1 < nt ? t + 1 : t) * 64;
    uint4 kreg = *(const uint4*)(kh + (size_t)(tn0 + sr) * HD + scol * 8);
    uint4 vreg = *(const uint4*)(vh + (size_t)sr * S_LEN + tn0 + scol * 8);

    const int dmax = r0 + 15 - t0;
    if (dmax >= 0) {
      f32x4 sc[4] = {};
      const int cmax = dmax >> 4;
      __builtin_amdgcn_s_setprio(1);
#pragma unroll
      for (int c = 0; c < 4; ++c) {
        if (c <= cmax) {
#pragma unroll
          for (int kk = 0; kk < 2; ++kk) {
            bf16x8 ka = *(const bf16x8*)(
                &Ks[cur][(c * 16 + lrow) * 64 + (((kk * 4 + lgrp) ^ (lrow & 7)) * 8)]);
            sc[c] = __builtin_amdgcn_mfma_f32_16x16x32_bf16(ka, qa[kk], sc[c], 0, 0, 0);
          }
        }
      }
      __builtin_amdgcn_s_setprio(0);

      // ---- causal mask (scores already in log2 domain via Q prescale) ----
      float p[16];
      const int q = r0 + lrow;
      if (t0 + 63 <= r0) {
#pragma unroll
        for (int c = 0; c < 4; ++c)
#pragma unroll
          for (int j = 0; j < 4; ++j)
            p[c * 4 + j] = sc[c][j];
      } else {
#pragma unroll
        for (int c = 0; c < 4; ++c)
#pragma unroll
          for (int j = 0; j < 4; ++j) {
            int kv = t0 + c * 16 + lgrp * 4 + j;
            p[c * 4 + j] = (kv <= q) ? sc[c][j] : -3.0e38f;
          }
      }

      // ---- row max: max3-friendly tree + 2 shuffles ----
      float m8[8];
#pragma unroll
      for (int i = 0; i < 8; ++i) m8[i] = fmaxf(p[i], p[i + 8]);
      float t1 = fmaxf(fmaxf(m8[0], m8[1]), m8[2]);
      float t2 = fmaxf(fmaxf(m8[3], m8[4]), m8[5]);
      float t3 = fmaxf(m8[6], m8[7]);
      float mx = fmaxf(fmaxf(t1, t2), t3);
      mx = fmaxf(mx, __shfl_xor(mx, 16, 64));
      mx = fmaxf(mx, __shfl_xor(mx, 32, 64));

      if (__all(mx <= m_col + 8.f)) {
        // defer: alpha == 1
      } else {
        float nm = fmaxf(m_col, mx);
        float alpha = __builtin_amdgcn_exp2f(m_col - nm);
        m_col = nm;
        float ar[4];
#pragma unroll
        for (int j = 0; j < 4; ++j)
          ar[j] = __shfl(alpha, lgrp * 4 + j, 64);
#pragma unroll
        for (int nf = 0; nf < 4; ++nf)
#pragma unroll
          for (int j = 0; j < 4; ++j)
            oacc[nf][j] *= ar[j];
        l_col *= alpha;
      }

#pragma unroll
      for (int i = 0; i < 16; ++i)
        p[i] = __builtin_amdgcn_exp2f(p[i] - m_col);
      float s8[8], s4[4];
#pragma unroll
      for (int i = 0; i < 8; ++i) s8[i] = p[i] + p[i + 8];
#pragma unroll
      for (int i = 0; i < 4; ++i) s4[i] = s8[i] + s8[i + 4];
      float rs = (s4[0] + s4[1]) + (s4[2] + s4[3]);
      rs += __shfl_xor(rs, 16, 64);
      rs += __shfl_xor(rs, 32, 64);
      l_col += rs;

#pragma unroll
      for (int c = 0; c < 4; ++c)
#pragma unroll
        for (int e = 0; e < 2; ++e) {
          union { __bf16 hh[2]; unsigned u; } pk;
          pk.hh[0] = (__bf16)p[c * 4 + 2 * e];
          pk.hh[1] = (__bf16)p[c * 4 + 2 * e + 1];
          *(unsigned*)&lds_p[wave][lrow][c * 16 + lgrp * 4 + 2 * e] = pk.u;
        }
      asm volatile("s_waitcnt lgkmcnt(0)" ::: "memory");

      bf16x8 pa0 = *(const bf16x8*)&lds_p[wave][lrow][lk];
      __builtin_amdgcn_s_setprio(1);
#pragma unroll
      for (int nf = 0; nf < 4; ++nf) {
        bf16x8 vb = *(const bf16x8*)(
            &Vs[cur][(nf * 16 + lrow) * 64 + ((lgrp ^ (lrow & 7)) * 8)]);
        oacc[nf] = __builtin_amdgcn_mfma_f32_16x16x32_bf16(pa0, vb, oacc[nf], 0, 0, 0);
      }
      __builtin_amdgcn_s_setprio(0);
      if (dmax >= 32) {
        bf16x8 pa1 = *(const bf16x8*)&lds_p[wave][lrow][32 + lk];
        __builtin_amdgcn_s_setprio(1);
#pragma unroll
        for (int nf = 0; nf < 4; ++nf) {
          bf16x8 vb = *(const bf16x8*)(
              &Vs[cur][(nf * 16 + lrow) * 64 + (((4 + lgrp) ^ (lrow & 7)) * 8)]);
          oacc[nf] = __builtin_amdgcn_mfma_f32_16x16x32_bf16(pa1, vb, oacc[nf], 0, 0, 0);
        }
        __builtin_amdgcn_s_setprio(0);
      }
    }

    *(uint4*)(&Ks[cur ^ 1][sr * 64 + dcol * 8]) = kreg;
    *(uint4*)(&Vs[cur ^ 1][sr * 64 + dcol * 8]) = vreg;
    __syncthreads();
  }

  float rlr[4];
#pragma unroll
  for (int j = 0; j < 4; ++j)
    rlr[j] = 1.0f / __shfl(l_col, lgrp * 4 + j, 64);
#pragma unroll
  for (int nf = 0; nf < 4; ++nf)
#pragma unroll
    for (int j = 0; j < 4; ++j) {
      int row = r0 + lgrp * 4 + j;
      attn_buf[(size_t)row * (NH * HD) + h * HD + nf * 16 + lrow] =
          (__bf16)(oacc[nf][j] * rlr[j]);
    }
}

extern "C" void kernel_launch(void* const* d_in, const int* in_sizes, int n_in,
                              void* d_out, int out_size, void* d_ws, size_t ws_size,
                              hipStream_t stream)
{
  const float* x  = (const float*)d_in[0];
  const float* wq = (const float*)d_in[1];
  const float* wk = (const float*)d_in[2];
  const float* wv = (const float*)d_in[3];
  const float* wo = (const float*)d_in[4];
  const float* fc = (const float*)d_in[5];
  float* out = (float*)d_out;

  char* ws = (char*)d_ws;
  __bf16* q_buf    = (__bf16*)(ws);                       //  8 MB [NH][S][HD]
  __bf16* k_buf    = (__bf16*)(ws +  8u * 1024 * 1024);   //  2 MB [NKV][S][HD]
  __bf16* v_buf    = (__bf16*)(ws + 10u * 1024 * 1024);   //  2 MB [NKV][HD][S]
  __bf16* attn_buf = (__bf16*)(ws + 12u * 1024 * 1024);   //  8 MB [S][NH*HD]
  __bf16* xb       = (__bf16*)(ws + 20u * 1024 * 1024);   //  8 MB [S][DIM]
  __bf16* wb       = (__bf16*)(ws + 28u * 1024 * 1024);   // 12 MB [3072][DIM]
  __bf16* wob      = (__bf16*)(ws + 40u * 1024 * 1024);   //  8 MB [DIM][DIM]

  cvt_xw<<<dim3(1792), 256, 0, stream>>>(x, wq, wk, wv, wo, xb, wb, wob);
  qkv_gemm<<<dim3(768), 256, 0, stream>>>(xb, wb, q_buf, k_buf, v_buf);
  rope_k<<<dim3(2048), 256, 0, stream>>>(k_buf, fc);
  attn_kernel<<<dim3(512), 512, 0, stream>>>(q_buf, k_buf, v_buf, fc, attn_buf);
  oproj_gemm<<<dim3(512), 256, 0, stream>>>(attn_buf, wob, out);
}

// Round 13
// 136.812 us; speedup vs baseline: 1.1501x; 1.0894x over previous
//
#include <hip/hip_runtime.h>
#include <hip/hip_bf16.h>

#define S_LEN 2048
#define DIM_  2048
#define NH    32
#define NKV   8
#define HD    64

typedef __bf16 bf16x8 __attribute__((ext_vector_type(8)));
typedef __bf16 bf16x4 __attribute__((ext_vector_type(4)));
typedef float  f32x4  __attribute__((ext_vector_type(4)));

#define AS_GLOBAL(p) ((const __attribute__((address_space(1))) void*)(p))
#define AS_LDS(p)    ((__attribute__((address_space(3))) void*)(p))

__device__ __forceinline__ bf16x8 pack8(float4 a, float4 b) {
  bf16x8 r;
  r[0] = (__bf16)a.x; r[1] = (__bf16)a.y; r[2] = (__bf16)a.z; r[3] = (__bf16)a.w;
  r[4] = (__bf16)b.x; r[5] = (__bf16)b.y; r[6] = (__bf16)b.z; r[7] = (__bf16)b.w;
  return r;
}

// ---------------- fp32 -> bf16 conversion with CHUNK SWIZZLE ----------------
// All matrices have 2048 cols. 16B chunk j (8 elems) of a matrix is stored at
// position j ^ ((j>>8)&7): XOR the 3-bit chunk-in-64-elem-segment index with
// (row&7). gload_lds then stages rows linearly -> LDS is swizzled -> the
// fragment ds_read_b128 (XOR fr&7) is 2-way bank-conflict-free.
// 1792 blocks x 256 thr x 4 chunks = 1,835,008 chunks exactly.
__global__ __launch_bounds__(256) void cvt_xw(
    const float* __restrict__ x,  const float* __restrict__ wq,
    const float* __restrict__ wk, const float* __restrict__ wv,
    const float* __restrict__ wo,
    __bf16* __restrict__ xb, __bf16* __restrict__ wb, __bf16* __restrict__ wob)
{
  const size_t stride = 458752;   // 1792 * 256
  size_t base = (size_t)blockIdx.x * 256 + threadIdx.x;
#pragma unroll
  for (int k = 0; k < 4; ++k) {
    size_t i = base + (size_t)k * stride;   // global chunk index
    const float* src; __bf16* dst; size_t j;
    if (i < 524288)       { src = x;  dst = xb;            j = i; }
    else if (i < 1048576) { src = wq; dst = wb;            j = i - 524288; }
    else if (i < 1179648) { src = wk; dst = wb + 4194304;  j = i - 1048576; }
    else if (i < 1310720) { src = wv; dst = wb + 5242880;  j = i - 1179648; }
    else                  { src = wo; dst = wob;           j = i - 1310720; }
    float4 f0 = ((const float4*)src)[j * 2];
    float4 f1 = ((const float4*)src)[j * 2 + 1];
    ((bf16x8*)dst)[j ^ ((j >> 8) & 7)] = pack8(f0, f1);
  }
}

// ------ 128x64-out GEMM tile, BK=64, 256 thr / 4 waves, global_load_lds -----
// A tile 128x64 (16 KB), B tile 64x64 (8 KB), double-buffered (48 KB LDS,
// 3 blocks/CU). BK=64 halves barrier-drain events vs BK=32; the global
// pre-swizzle makes the 128B-row fragment reads 2-way conflict-free.
#define BK 64
#define TA_ELEMS 8192   // 128*64
#define TB_ELEMS 4096   //  64*64

// 256 threads stage a 128x64 tile (16 KB): four 16B chunks each.
__device__ __forceinline__ void stage_A(
    const __bf16* __restrict__ g, int row0, int k0, int ld, __bf16* lds)
{
  const int tid = threadIdx.x;
  const int wave = tid >> 6;
#pragma unroll
  for (int iss = 0; iss < 4; ++iss) {
    int off = (iss * 256 + tid) * 16;   // byte offset in 16 KB tile
    int r = off >> 7;                   // 128 B per row (64 bf16)
    int c = (off & 127) >> 1;           // physical bf16 col (pre-swizzled)
    __builtin_amdgcn_global_load_lds(
        AS_GLOBAL(g + (size_t)(row0 + r) * ld + k0 + c),
        AS_LDS(lds + iss * 2048 + wave * 512),   // wave-uniform base + lane*16
        16, 0, 0);
  }
}

// 256 threads stage a 64x64 tile (8 KB): two 16B chunks each.
__device__ __forceinline__ void stage_B(
    const __bf16* __restrict__ g, int row0, int k0, int ld, __bf16* lds)
{
  const int tid = threadIdx.x;
  const int wave = tid >> 6;
#pragma unroll
  for (int iss = 0; iss < 2; ++iss) {
    int off = (iss * 256 + tid) * 16;
    int r = off >> 7;
    int c = (off & 127) >> 1;
    __builtin_amdgcn_global_load_lds(
        AS_GLOBAL(g + (size_t)(row0 + r) * ld + k0 + c),
        AS_LDS(lds + iss * 2048 + wave * 512), 16, 0, 0);
  }
}

__device__ __forceinline__ void gemm_mainloop(
    const __bf16* __restrict__ A, const __bf16* __restrict__ B,
    int row0, int col0, int lda, int ldb, int nt,
    __bf16* As, __bf16* Bs, f32x4 acc[4][2])
{
  const int lane = threadIdx.x & 63;
  const int wave = threadIdx.x >> 6;
  const int wr = wave >> 1, wc = wave & 1;   // 2x2 wave grid
  const int fr = lane & 15, fg = lane >> 4;
  const int sw = fr & 7;                     // read-side chunk XOR

  stage_A(A, row0, 0, lda, As);
  stage_B(B, col0, 0, ldb, Bs);

  for (int t = 0; t < nt; ++t) {
    const int cur = t & 1;
    if (t + 1 < nt) {
      stage_A(A, row0, (t + 1) * BK, lda, As + (cur ^ 1) * TA_ELEMS);
      stage_B(B, col0, (t + 1) * BK, ldb, Bs + (cur ^ 1) * TB_ELEMS);
    }
    __syncthreads();
#pragma unroll
    for (int kk = 0; kk < 2; ++kk) {
      bf16x8 a[4], b[2];
#pragma unroll
      for (int mi = 0; mi < 4; ++mi)
        a[mi] = *(const bf16x8*)(As + cur * TA_ELEMS +
                 (wr * 64 + mi * 16 + fr) * 64 + (((kk * 4 + fg) ^ sw) * 8));
#pragma unroll
      for (int ni = 0; ni < 2; ++ni)
        b[ni] = *(const bf16x8*)(Bs + cur * TB_ELEMS +
                 (wc * 32 + ni * 16 + fr) * 64 + (((kk * 4 + fg) ^ sw) * 8));
#pragma unroll
      for (int mi = 0; mi < 4; ++mi)
#pragma unroll
        for (int ni = 0; ni < 2; ++ni)
          acc[mi][ni] = __builtin_amdgcn_mfma_f32_16x16x32_bf16(a[mi], b[ni], acc[mi][ni], 0, 0, 0);
    }
    __syncthreads();
  }
}

// ---------------- QKV projection (bf16-swz, 768 blocks = 3/CU) --------------
__global__ __launch_bounds__(256) void qkv_gemm(
    const __bf16* __restrict__ xb, const __bf16* __restrict__ wb,
    __bf16* __restrict__ q_buf, __bf16* __restrict__ k_buf, __bf16* __restrict__ v_buf)
{
  __shared__ __bf16 As[2 * TA_ELEMS];   // 32 KB
  __shared__ __bf16 Bs[2 * TB_ELEMS];   // 16 KB
  const int lane = threadIdx.x & 63;
  const int wave = threadIdx.x >> 6;
  const int wr = wave >> 1, wc = wave & 1;
  const int fr = lane & 15, fg = lane >> 4;

  const int lid = blockIdx.x;        // 0..767
  const int xcd = lid & 7;
  const int i   = lid >> 3;          // 0..95
  const int row0 = (i & 15) * 128;
  const int col0 = (xcd * 6 + (i >> 4)) * 64;

  f32x4 acc[4][2] = {};
  gemm_mainloop(xb, wb, row0, col0, DIM_, DIM_, DIM_ / BK, As, Bs, acc);

  const int rowg0 = row0 + wr * 64;
  const int colg0 = col0 + wc * 32;
#pragma unroll
  for (int mi = 0; mi < 4; ++mi) {
#pragma unroll
    for (int ni = 0; ni < 2; ++ni) {
#pragma unroll
      for (int j = 0; j < 4; ++j) {
        int row = rowg0 + mi * 16 + fg * 4 + j;
        int col = colg0 + ni * 16 + fr;
        float v = acc[mi][ni][j];
        if (col < 2048) {
          int h = col >> 6, d = col & 63;
          q_buf[((size_t)h * S_LEN + row) * HD + d] = (__bf16)v;
        } else if (col < 2560) {
          int c = col - 2048, g = c >> 6, d = c & 63;
          k_buf[((size_t)g * S_LEN + row) * HD + d] = (__bf16)v;
        } else {
          int c = col - 2560, g = c >> 6, d = c & 63;
          v_buf[((size_t)g * HD + d) * S_LEN + row] = (__bf16)v;  // transposed
        }
      }
    }
  }
}

// ---------------- Output projection (bf16-swz, 512 blocks) ------------------
__global__ __launch_bounds__(256) void oproj_gemm(
    const __bf16* __restrict__ attn_buf, const __bf16* __restrict__ wob,
    float* __restrict__ out)
{
  __shared__ __bf16 As[2 * TA_ELEMS];
  __shared__ __bf16 Bs[2 * TB_ELEMS];
  const int lane = threadIdx.x & 63;
  const int wave = threadIdx.x >> 6;
  const int wr = wave >> 1, wc = wave & 1;
  const int fr = lane & 15, fg = lane >> 4;

  const int lid = blockIdx.x;        // 0..511
  const int xcd = lid & 7;
  const int i   = lid >> 3;          // 0..63
  const int row0 = (i & 15) * 128;
  const int col0 = (xcd * 4 + (i >> 4)) * 64;

  f32x4 acc[4][2] = {};
  gemm_mainloop(attn_buf, wob, row0, col0, DIM_, DIM_, DIM_ / BK, As, Bs, acc);

  const int rowg0 = row0 + wr * 64;
  const int colg0 = col0 + wc * 32;
#pragma unroll
  for (int mi = 0; mi < 4; ++mi)
#pragma unroll
    for (int ni = 0; ni < 2; ++ni)
#pragma unroll
      for (int j = 0; j < 4; ++j) {
        int row = rowg0 + mi * 16 + fg * 4 + j;
        int col = colg0 + ni * 16 + fr;
        out[(size_t)row * DIM_ + col] = acc[mi][ni][j];
      }
}

// ---------------- RoPE on K only (in place, bf16); Q fused into attn --------
__global__ __launch_bounds__(256) void rope_k(
    __bf16* __restrict__ k_buf, const float* __restrict__ fc)
{
  int idx = blockIdx.x * 256 + threadIdx.x;
  int i    = idx & 31;
  int sp   = (idx >> 5) & (S_LEN - 1);
  int g    = idx >> 16;
  __bf16* buf = k_buf + ((size_t)g * S_LEN + sp) * HD;
  float c = fc[(sp * 32 + i) * 2 + 0];
  float s = fc[(sp * 32 + i) * 2 + 1];
  float x1 = (float)buf[2 * i], x2 = (float)buf[2 * i + 1];
  buf[2 * i + 0] = (__bf16)(x1 * c - x2 * s);
  buf[2 * i + 1] = (__bf16)(x1 * s + x2 * c);
}

// ---------------- Flash attention (causal, GQA, swapped-QK, shared KV) ------
// 1-D grid 512, PAIRED dispatch. Epilogue writes attn_buf with the same
// chunk swizzle (col-chunk ^ row&7) so oproj's gload_lds staging is swizzled.
__global__ __launch_bounds__(512) void attn_kernel(
    const __bf16* __restrict__ q_buf, const __bf16* __restrict__ k_buf,
    const __bf16* __restrict__ v_buf, const float* __restrict__ fc,
    __bf16* __restrict__ attn_buf)
{
  __shared__ __align__(16) __bf16 Ks[2][64 * 64];   // 2 x 8 KB
  __shared__ __align__(16) __bf16 Vs[2][64 * 64];   // 2 x 8 KB (V^T: [d][kv])
  __shared__ __align__(16) __bf16 lds_p[8][16][72]; // per-wave P slab

  const int tid  = threadIdx.x;
  const int lane = tid & 63;
  const int wave = tid >> 6;
  const int n = blockIdx.x;
  const int qt = (n < 256) ? (15 - (n >> 5)) : ((n - 256) >> 5);
  const int h  = n & 31;
  const int g = h >> 2;             // NREP = 4
  const int r0 = qt * 128 + wave * 16;
  const int lrow = lane & 15;
  const int lgrp = lane >> 4;
  const int lk = lgrp * 8;

  const __bf16* qh = q_buf + (size_t)h * S_LEN * HD;
  const __bf16* kh = k_buf + (size_t)g * S_LEN * HD;
  const __bf16* vh = v_buf + (size_t)g * HD * S_LEN;

  const int sr   = tid >> 3;            // staging row 0..63
  const int scol = tid & 7;             // source 16B chunk
  const int dcol = scol ^ (sr & 7);     // swizzled dest chunk

  // ---- load Q fragment + RoPE with KS-folded coefficients ----
  const float KS = 0.125f * 1.44269504088896f;  // scale * log2(e)
  bf16x8 qa[2];
  const float* fcrow = fc + (size_t)(r0 + lrow) * 64;
#pragma unroll
  for (int kk = 0; kk < 2; ++kk) {
    qa[kk] = *(const bf16x8*)(qh + (size_t)(r0 + lrow) * HD + kk * 32 + lk);
    float4 cs0 = *(const float4*)(fcrow + (kk * 16 + lgrp * 4) * 2);
    float4 cs1 = *(const float4*)(fcrow + (kk * 16 + lgrp * 4) * 2 + 4);
    float cc[4] = {cs0.x * KS, cs0.z * KS, cs1.x * KS, cs1.z * KS};
    float ss[4] = {cs0.y * KS, cs0.w * KS, cs1.y * KS, cs1.w * KS};
#pragma unroll
    for (int pr = 0; pr < 4; ++pr) {
      float x1 = (float)qa[kk][2 * pr], x2 = (float)qa[kk][2 * pr + 1];
      qa[kk][2 * pr]     = (__bf16)(x1 * cc[pr] - x2 * ss[pr]);
      qa[kk][2 * pr + 1] = (__bf16)(x1 * ss[pr] + x2 * cc[pr]);
    }
  }

  float m_col = -3.0e38f, l_col = 0.f;
  f32x4 oacc[4] = {};

  const int nt = 2 * qt + 2;

  {
    uint4 k0 = *(const uint4*)(kh + (size_t)sr * HD + scol * 8);
    uint4 v0 = *(const uint4*)(vh + (size_t)sr * S_LEN + scol * 8);
    *(uint4*)(&Ks[0][sr * 64 + dcol * 8]) = k0;
    *(uint4*)(&Vs[0][sr * 64 + dcol * 8]) = v0;
  }
  __syncthreads();

  for (int t = 0; t < nt; ++t) {
    const int cur = t & 1;
    const int t0 = t * 64;

    const int tn0 = (t + 1 < nt ? t + 1 : t) * 64;
    uint4 kreg = *(const uint4*)(kh + (size_t)(tn0 + sr) * HD + scol * 8);
    uint4 vreg = *(const uint4*)(vh + (size_t)sr * S_LEN + tn0 + scol * 8);

    const int dmax = r0 + 15 - t0;
    if (dmax >= 0) {
      f32x4 sc[4] = {};
      const int cmax = dmax >> 4;
      __builtin_amdgcn_s_setprio(1);
#pragma unroll
      for (int c = 0; c < 4; ++c) {
        if (c <= cmax) {
#pragma unroll
          for (int kk = 0; kk < 2; ++kk) {
            bf16x8 ka = *(const bf16x8*)(
                &Ks[cur][(c * 16 + lrow) * 64 + (((kk * 4 + lgrp) ^ (lrow & 7)) * 8)]);
            sc[c] = __builtin_amdgcn_mfma_f32_16x16x32_bf16(ka, qa[kk], sc[c], 0, 0, 0);
          }
        }
      }
      __builtin_amdgcn_s_setprio(0);

      float p[16];
      const int q = r0 + lrow;
      if (t0 + 63 <= r0) {
#pragma unroll
        for (int c = 0; c < 4; ++c)
#pragma unroll
          for (int j = 0; j < 4; ++j)
            p[c * 4 + j] = sc[c][j];
      } else {
#pragma unroll
        for (int c = 0; c < 4; ++c)
#pragma unroll
          for (int j = 0; j < 4; ++j) {
            int kv = t0 + c * 16 + lgrp * 4 + j;
            p[c * 4 + j] = (kv <= q) ? sc[c][j] : -3.0e38f;
          }
      }

      float m8[8];
#pragma unroll
      for (int i = 0; i < 8; ++i) m8[i] = fmaxf(p[i], p[i + 8]);
      float t1 = fmaxf(fmaxf(m8[0], m8[1]), m8[2]);
      float t2 = fmaxf(fmaxf(m8[3], m8[4]), m8[5]);
      float t3 = fmaxf(m8[6], m8[7]);
      float mx = fmaxf(fmaxf(t1, t2), t3);
      mx = fmaxf(mx, __shfl_xor(mx, 16, 64));
      mx = fmaxf(mx, __shfl_xor(mx, 32, 64));

      if (__all(mx <= m_col + 8.f)) {
        // defer: alpha == 1
      } else {
        float nm = fmaxf(m_col, mx);
        float alpha = __builtin_amdgcn_exp2f(m_col - nm);
        m_col = nm;
        float ar[4];
#pragma unroll
        for (int j = 0; j < 4; ++j)
          ar[j] = __shfl(alpha, lgrp * 4 + j, 64);
#pragma unroll
        for (int nf = 0; nf < 4; ++nf)
#pragma unroll
          for (int j = 0; j < 4; ++j)
            oacc[nf][j] *= ar[j];
        l_col *= alpha;
      }

#pragma unroll
      for (int i = 0; i < 16; ++i)
        p[i] = __builtin_amdgcn_exp2f(p[i] - m_col);
      float s8[8], s4[4];
#pragma unroll
      for (int i = 0; i < 8; ++i) s8[i] = p[i] + p[i + 8];
#pragma unroll
      for (int i = 0; i < 4; ++i) s4[i] = s8[i] + s8[i + 4];
      float rs = (s4[0] + s4[1]) + (s4[2] + s4[3]);
      rs += __shfl_xor(rs, 16, 64);
      rs += __shfl_xor(rs, 32, 64);
      l_col += rs;

#pragma unroll
      for (int c = 0; c < 4; ++c)
#pragma unroll
        for (int e = 0; e < 2; ++e) {
          union { __bf16 hh[2]; unsigned u; } pk;
          pk.hh[0] = (__bf16)p[c * 4 + 2 * e];
          pk.hh[1] = (__bf16)p[c * 4 + 2 * e + 1];
          *(unsigned*)&lds_p[wave][lrow][c * 16 + lgrp * 4 + 2 * e] = pk.u;
        }
      asm volatile("s_waitcnt lgkmcnt(0)" ::: "memory");

      bf16x8 pa0 = *(const bf16x8*)&lds_p[wave][lrow][lk];
      __builtin_amdgcn_s_setprio(1);
#pragma unroll
      for (int nf = 0; nf < 4; ++nf) {
        bf16x8 vb = *(const bf16x8*)(
            &Vs[cur][(nf * 16 + lrow) * 64 + ((lgrp ^ (lrow & 7)) * 8)]);
        oacc[nf] = __builtin_amdgcn_mfma_f32_16x16x32_bf16(pa0, vb, oacc[nf], 0, 0, 0);
      }
      __builtin_amdgcn_s_setprio(0);
      if (dmax >= 32) {
        bf16x8 pa1 = *(const bf16x8*)&lds_p[wave][lrow][32 + lk];
        __builtin_amdgcn_s_setprio(1);
#pragma unroll
        for (int nf = 0; nf < 4; ++nf) {
          bf16x8 vb = *(const bf16x8*)(
              &Vs[cur][(nf * 16 + lrow) * 64 + (((4 + lgrp) ^ (lrow & 7)) * 8)]);
          oacc[nf] = __builtin_amdgcn_mfma_f32_16x16x32_bf16(pa1, vb, oacc[nf], 0, 0, 0);
        }
        __builtin_amdgcn_s_setprio(0);
      }
    }

    *(uint4*)(&Ks[cur ^ 1][sr * 64 + dcol * 8]) = kreg;
    *(uint4*)(&Vs[cur ^ 1][sr * 64 + dcol * 8]) = vreg;
    __syncthreads();
  }

  // ---- epilogue: divide by row-sum; store with chunk swizzle (^row&7) ----
  float rlr[4];
#pragma unroll
  for (int j = 0; j < 4; ++j)
    rlr[j] = 1.0f / __shfl(l_col, lgrp * 4 + j, 64);
#pragma unroll
  for (int nf = 0; nf < 4; ++nf)
#pragma unroll
    for (int j = 0; j < 4; ++j) {
      int row = r0 + lgrp * 4 + j;
      int col = h * HD + nf * 16 + lrow;
      int ch  = (((col >> 3) & 7) ^ (row & 7));
      int cols = (col & 7) | (ch << 3) | (col & ~63);
      attn_buf[(size_t)row * (NH * HD) + cols] =
          (__bf16)(oacc[nf][j] * rlr[j]);
    }
}

extern "C" void kernel_launch(void* const* d_in, const int* in_sizes, int n_in,
                              void* d_out, int out_size, void* d_ws, size_t ws_size,
                              hipStream_t stream)
{
  const float* x  = (const float*)d_in[0];
  const float* wq = (const float*)d_in[1];
  const float* wk = (const float*)d_in[2];
  const float* wv = (const float*)d_in[3];
  const float* wo = (const float*)d_in[4];
  const float* fc = (const float*)d_in[5];
  float* out = (float*)d_out;

  char* ws = (char*)d_ws;
  __bf16* q_buf    = (__bf16*)(ws);                       //  8 MB [NH][S][HD]
  __bf16* k_buf    = (__bf16*)(ws +  8u * 1024 * 1024);   //  2 MB [NKV][S][HD]
  __bf16* v_buf    = (__bf16*)(ws + 10u * 1024 * 1024);   //  2 MB [NKV][HD][S]
  __bf16* attn_buf = (__bf16*)(ws + 12u * 1024 * 1024);   //  8 MB [S][NH*HD] swz
  __bf16* xb       = (__bf16*)(ws + 20u * 1024 * 1024);   //  8 MB [S][DIM] swz
  __bf16* wb       = (__bf16*)(ws + 28u * 1024 * 1024);   // 12 MB [3072][DIM] swz
  __bf16* wob      = (__bf16*)(ws + 40u * 1024 * 1024);   //  8 MB [DIM][DIM] swz

  cvt_xw<<<dim3(1792), 256, 0, stream>>>(x, wq, wk, wv, wo, xb, wb, wob);
  qkv_gemm<<<dim3(768), 256, 0, stream>>>(xb, wb, q_buf, k_buf, v_buf);
  rope_k<<<dim3(2048), 256, 0, stream>>>(k_buf, fc);
  attn_kernel<<<dim3(512), 512, 0, stream>>>(q_buf, k_buf, v_buf, fc, attn_buf);
  oproj_gemm<<<dim3(512), 256, 0, stream>>>(attn_buf, wob, out);
}